// Round 1
// baseline (30.978 us; speedup 1.0000x reference)
//
#include <hip/hip_runtime.h>

#define NPROPS 32
#define MAXN   8192
#define MARGIN 1.0f

// Workspace layout in d_ws (zero-initialized where needed by compact_kernel
// every call -> deterministic under graph replay).
struct Ws {
    double    loss_acc;             // accumulated hinge sum
    long long num_pairs;            // sum_p n_pos[p] * n_neg[p]
    int       total_pos;            // number of label==1 elements
    int       neg_base[NPROPS + 1]; // prefix offsets of negatives per property
    int       pos_pid[MAXN];        // property id of each compacted positive
    float     pos_score[MAXN];      // compacted positive scores
    float     neg_score[MAXN];      // compacted negative scores, grouped by pid
};

// ---------------------------------------------------------------------------
// Kernel 1: counting-sort compaction into (property,label) buckets.
// Single block, 1024 threads: 8192 elements -> trivial.
// ---------------------------------------------------------------------------
__global__ __launch_bounds__(1024)
void compact_kernel(const float* __restrict__ scores,
                    const int*   __restrict__ labels,
                    const int*   __restrict__ pids,
                    Ws* __restrict__ ws, int n) {
    __shared__ int cnt[64];    // buckets: [0..31]=neg per pid, [32..63]=pos per pid
    __shared__ int base[64];
    const int tid = threadIdx.x;

    if (tid < 64) cnt[tid] = 0;
    __syncthreads();

    for (int i = tid; i < n; i += blockDim.x) {
        int b = pids[i] + (labels[i] << 5);
        atomicAdd(&cnt[b], 1);
    }
    __syncthreads();

    if (tid == 0) {
        int negOff = 0;
        for (int p = 0; p < NPROPS; ++p) {
            ws->neg_base[p] = negOff;
            base[p] = negOff;
            negOff += cnt[p];
        }
        ws->neg_base[NPROPS] = negOff;

        int posOff = 0;
        long long pairs = 0;
        for (int p = 0; p < NPROPS; ++p) {
            base[32 + p] = posOff;
            posOff += cnt[32 + p];
            pairs  += (long long)cnt[32 + p] * (long long)cnt[p];
        }
        ws->total_pos = posOff;
        ws->num_pairs = pairs;
        ws->loss_acc  = 0.0;   // re-zero every call (ws is poisoned once)
    }
    __syncthreads();

    // reuse cnt[] as scatter cursors
    if (tid < 64) cnt[tid] = base[tid];
    __syncthreads();

    for (int i = tid; i < n; i += blockDim.x) {
        int   lab = labels[i];
        int   pid = pids[i];
        int   b   = pid + (lab << 5);
        int   idx = atomicAdd(&cnt[b], 1);
        float s   = scores[i];
        if (lab) {
            ws->pos_score[idx] = s;
            ws->pos_pid[idx]   = pid;
        } else {
            ws->neg_score[idx] = s;
        }
    }
}

// ---------------------------------------------------------------------------
// Kernel 2: for each positive, sweep the negatives of its property.
// Compacted data (~96 KB) is L1/L2 resident. Per-thread f32 partials,
// wave shuffle reduce, one f64 atomicAdd per block.
// ---------------------------------------------------------------------------
__global__ __launch_bounds__(256)
void pair_kernel(Ws* __restrict__ ws) {
    const int total_pos = ws->total_pos;
    float acc = 0.0f;

    for (int idx = blockIdx.x * blockDim.x + threadIdx.x; idx < total_pos;
         idx += gridDim.x * blockDim.x) {
        const float si = ws->pos_score[idx];
        const int   p  = ws->pos_pid[idx];
        const int   j0 = ws->neg_base[p];
        const int   j1 = ws->neg_base[p + 1];
        const float a  = MARGIN - si;
        for (int j = j0; j < j1; ++j) {
            acc += fmaxf(a + ws->neg_score[j], 0.0f);
        }
    }

    // wave64 reduction
    #pragma unroll
    for (int off = 32; off > 0; off >>= 1)
        acc += __shfl_down(acc, off);

    __shared__ float wsum[4];
    const int lane = threadIdx.x & 63;
    const int wid  = threadIdx.x >> 6;
    if (lane == 0) wsum[wid] = acc;
    __syncthreads();

    if (threadIdx.x == 0) {
        float s = wsum[0] + wsum[1] + wsum[2] + wsum[3];
        atomicAdd(&ws->loss_acc, (double)s);
    }
}

// ---------------------------------------------------------------------------
// Kernel 3: final division.
// ---------------------------------------------------------------------------
__global__ void finalize_kernel(const Ws* __restrict__ ws,
                                float* __restrict__ out) {
    long long np = ws->num_pairs;
    double loss  = ws->loss_acc;
    out[0] = (np == 0) ? 0.0f : (float)(loss / (double)np);
}

extern "C" void kernel_launch(void* const* d_in, const int* in_sizes, int n_in,
                              void* d_out, int out_size, void* d_ws, size_t ws_size,
                              hipStream_t stream) {
    const float* scores = (const float*)d_in[0];
    const int*   labels = (const int*)d_in[1];
    const int*   pids   = (const int*)d_in[2];
    const int    n      = in_sizes[0];
    Ws* ws = (Ws*)d_ws;

    compact_kernel<<<1, 1024, 0, stream>>>(scores, labels, pids, ws, n);
    pair_kernel<<<64, 256, 0, stream>>>(ws);
    finalize_kernel<<<1, 1, 0, stream>>>(ws, (float*)d_out);
}

// Round 2
// 13.551 us; speedup vs baseline: 2.2861x; 2.2861x over previous
//
#include <hip/hip_runtime.h>

#define NPROPS 32
#define MAXN   8192
#define MARGIN 1.0f

// Per-block partials; every block writes its own slot unconditionally every
// call -> no zero-init required, deterministic under graph replay.
struct Ws {
    double    loss[NPROPS];
    long long pairs[NPROPS];
};

// ---------------------------------------------------------------------------
// Kernel 1: one block per property. Scan all inputs (vectorized), bucket this
// property's pos/neg scores into LDS, compute all pos x neg hinge terms from
// LDS, block-reduce, write one partial per block.
// ---------------------------------------------------------------------------
__global__ __launch_bounds__(256)
void fused_kernel(const float* __restrict__ scores,
                  const int*   __restrict__ labels,
                  const int*   __restrict__ pids,
                  Ws* __restrict__ ws, int n) {
    const int p   = blockIdx.x;      // property this block owns
    const int tid = threadIdx.x;

    __shared__ float pos_s[MAXN];
    __shared__ float neg_s[MAXN];
    __shared__ int   cnt[2];         // [0] = #neg, [1] = #pos

    if (tid < 2) cnt[tid] = 0;
    __syncthreads();

    // Vectorized scan: n is a multiple of 1024 here (8192), 4 elems/thread/iter.
    const int4*   pid4v = (const int4*)pids;
    const int4*   lab4v = (const int4*)labels;
    const float4* sc4v  = (const float4*)scores;
    for (int v = tid; v * 4 < n; v += 256) {
        int4   pd = pid4v[v];
        int4   lb = lab4v[v];
        float4 sc = sc4v[v];
        #pragma unroll
        for (int k = 0; k < 4; ++k) {
            int   pk = (&pd.x)[k];
            int   lk = (&lb.x)[k];
            float sk = (&sc.x)[k];
            if (pk == p) {
                int idx = atomicAdd(&cnt[lk], 1);
                if (lk) pos_s[idx] = sk; else neg_s[idx] = sk;
            }
        }
    }
    __syncthreads();

    const int nneg = cnt[0];
    const int npos = cnt[1];

    // Pair sweep: thread t handles positives t, t+256, ... against all negs.
    float acc = 0.0f;
    for (int i = tid; i < npos; i += 256) {
        const float a = MARGIN - pos_s[i];
        for (int j = 0; j < nneg; ++j)
            acc += fmaxf(a + neg_s[j], 0.0f);
    }

    // wave64 shuffle reduce, then cross-wave via LDS
    #pragma unroll
    for (int off = 32; off > 0; off >>= 1)
        acc += __shfl_down(acc, off);

    __shared__ float wsum[4];
    const int lane = tid & 63, wid = tid >> 6;
    if (lane == 0) wsum[wid] = acc;
    __syncthreads();

    if (tid == 0) {
        ws->loss[p]  = (double)(wsum[0] + wsum[1] + wsum[2] + wsum[3]);
        ws->pairs[p] = (long long)npos * (long long)nneg;
    }
}

// ---------------------------------------------------------------------------
// Kernel 2: one wave reduces the 32 partials and writes the mean.
// ---------------------------------------------------------------------------
__global__ __launch_bounds__(64)
void finalize_kernel(const Ws* __restrict__ ws, float* __restrict__ out) {
    const int lane = threadIdx.x;
    double    l = (lane < NPROPS) ? ws->loss[lane]  : 0.0;
    long long c = (lane < NPROPS) ? ws->pairs[lane] : 0;
    #pragma unroll
    for (int off = 32; off > 0; off >>= 1) {
        l += __shfl_down(l, off);
        c += __shfl_down(c, off);
    }
    if (lane == 0) out[0] = (c == 0) ? 0.0f : (float)(l / (double)c);
}

extern "C" void kernel_launch(void* const* d_in, const int* in_sizes, int n_in,
                              void* d_out, int out_size, void* d_ws, size_t ws_size,
                              hipStream_t stream) {
    const float* scores = (const float*)d_in[0];
    const int*   labels = (const int*)d_in[1];
    const int*   pids   = (const int*)d_in[2];
    const int    n      = in_sizes[0];
    Ws* ws = (Ws*)d_ws;

    fused_kernel<<<NPROPS, 256, 0, stream>>>(scores, labels, pids, ws, n);
    finalize_kernel<<<1, 64, 0, stream>>>(ws, (float*)d_out);
}